// Round 2
// 433.384 us; speedup vs baseline: 1.0467x; 1.0467x over previous
//
#include <hip/hip_runtime.h>

// CrossAttention (B=8, Sq=Skv=2048, D=1024), fp32 in/out, bf16 MFMA compute.
//
// Full-batch pipeline (ws usage 107 MB; Q AND K parked in d_out as bf16):
//   1) cvt fp32->bf16: {x,ctx} -> xbf,cbf ; {Wq*(1/32),Wk,Wv} -> Wqb,Wkb,Wvb
//   2) [Q|K] = [x|ctx] @ [Wq|Wk]^T  (one batched NT GEMM) -> d_out bf16
//      Vt[b,e,t] = Wv@ctx^T (V transposed so PV is NT)    -> ws
//   3) S[b,s,t] = Q@K^T (8 batches) -> bf16 S overlays dead xbf+cbf
//   4) softmax rows in place (16384 rows)
//   5) out = P@Vt^T (f32) -> d_out, overwriting dead Q/K (stream-ordered)
//
// GEMM: 256x256 tile, BK=64, 8 waves (2Mx4N, each 128x64 via 8x4 frags of
// mfma_f32_16x16x32_bf16), 128 KiB STATIC LDS double buffer (static, not
// dynamic: avoids the >64KB dynamic-sharedMem launch-validation path).
// Deep-pipelined schedule (T2+T3+T4+T5):
//   - each K-tile = 4 phases of 16 MFMA; tile t+1 staged one k-half per
//     phase into the idle buffer via global_load_lds width=16;
//   - counted s_waitcnt vmcnt(4) (never 0 in steady state) + raw s_barrier:
//     every wait retires only loads issued >=2 phases (~1000 cyc) earlier;
//   - LDS XOR swizzle slot^((row>>1)&3), applied on BOTH the pre-swizzled
//     global source column and the ds_read_b128 address (linear LDS dest,
//     rule "both-sides-or-neither") -> 2-way bank aliasing only (free);
//   - sched_barrier(0) AFTER each s_barrier blocks ds_read hoisting above
//     the barrier (the m152 race mode);
//   - s_setprio(1) around each MFMA cluster.
// 1D grid + XCD-aware swizzle: HW assigns XCD = blockIdx % 8 (round-robin);
// remap gid=(p%8)*slab+(p/8) gives each XCD a contiguous x-innermost slab.
// NOTE: grid size MUST equal nx*ny*nz exactly and be divisible by 8.

typedef unsigned short u16;
typedef __bf16 bf16x8 __attribute__((ext_vector_type(8)));
typedef float f32x4 __attribute__((ext_vector_type(4)));
typedef u16 us8 __attribute__((ext_vector_type(8)));

__device__ __forceinline__ u16 f2bf(float f) {
  unsigned int u = __float_as_uint(f);
  u += 0x7fffu + ((u >> 16) & 1u);   // round-to-nearest-even
  return (u16)(u >> 16);
}
__device__ __forceinline__ float bf2f(u16 h) {
  return __uint_as_float((unsigned int)h << 16);
}

struct __attribute__((aligned(8))) us4 { u16 x, y, z, w; };

// x (4194304 float4) -> xbf ; ctx -> cbf. One dispatch.
__global__ __launch_bounds__(256) void cvt_xc(const float4* __restrict__ x,
                                              const float4* __restrict__ c,
                                              us4* __restrict__ dx,
                                              us4* __restrict__ dc) {
  int i = blockIdx.x * 256 + threadIdx.x;
  const float4* s = (i < 4194304) ? x : (c - 4194304);
  us4* d = (i < 4194304) ? dx : (dc - 4194304);
  float4 v = s[i];
  us4 o{f2bf(v.x), f2bf(v.y), f2bf(v.z), f2bf(v.w)};
  d[i] = o;
}

// Wq*(1/32), Wk, Wv -> bf16 (each 262144 float4). One dispatch, 3072 blocks.
__global__ __launch_bounds__(256) void cvt_w(const float4* __restrict__ wq,
                                             const float4* __restrict__ wk,
                                             const float4* __restrict__ wv,
                                             us4* __restrict__ d) {
  int i = blockIdx.x * 256 + threadIdx.x;
  const float4* s; float sc;
  if (i < 262144)      { s = wq;           sc = 0.03125f; }
  else if (i < 524288) { s = wk - 262144;  sc = 1.0f; }
  else                 { s = wv - 524288;  sc = 1.0f; }
  float4 v = s[i];
  us4 o{f2bf(v.x * sc), f2bf(v.y * sc), f2bf(v.z * sc), f2bf(v.w * sc)};
  d[i] = o;
}

// C-style casts: static_cast cannot both drop const and change address space.
__device__ __forceinline__ void gload16(const u16* g, u16* l) {
  __builtin_amdgcn_global_load_lds(
      (const __attribute__((address_space(1))) unsigned int*)g,
      (__attribute__((address_space(3))) unsigned int*)l,
      16, 0, 0);
}

// NT GEMM: C[m,n] = sum_k A[m,k]*B[n,k].  A:[M][lda] B:[N][ldb] bf16
// row-major. 1D grid of EXACTLY nx*ny*nz blocks (divisible by 8), 512 thr.
template <bool BF16OUT>
__global__ __launch_bounds__(512, 2) void gemm_nt(
    const u16* __restrict__ A, const u16* __restrict__ B, void* __restrict__ Cout,
    int lda, int ldb, int ldc, int K,
    long batchA, long batchB, long batchC, int nx, int ny) {
  __shared__ u16 lds[65536];   // 128 KiB static
  // layout (u16 offs): buf b at b*32768; A k-half h at +h*8192 (256x32),
  // B at +16384 (+h*8192). Within a k-half: row r at r*32, 4 slots of 8.

  const int p    = blockIdx.x;
  const int slab = gridDim.x >> 3;
  const int gid  = (p & 7) * slab + (p >> 3);
  const int bx   = gid % nx;
  const int t2   = gid / nx;
  const int by   = t2 % ny;
  const int z    = t2 / ny;

  const int tid  = threadIdx.x;          // 0..511
  const int lane = tid & 63;
  const int wv   = tid >> 6;             // wave 0..7

  const u16* Ab = A + (size_t)z * batchA + (size_t)by * 256 * lda;
  const u16* Bb = B + (size_t)z * batchB + (size_t)bx * 256 * ldb;

  // staging: 512 threads, 4/row (64-B runs), 2 instrs cover 256 rows.
  // global col-group pre-swizzled: c = (tid&3) ^ ((row>>1)&3), row=tid>>2.
  const int srow = tid >> 2;                              // 0..127
  const int scol = ((tid & 3) ^ ((tid >> 3) & 3)) * 8;    // swizzled source

  const u16* gA = Ab + (size_t)srow * lda + scol;
  const u16* gB = Bb + (size_t)srow * ldb + scol;
  const size_t a128 = (size_t)128 * lda, b128 = (size_t)128 * ldb;

  u16* dA = &lds[tid * 8];           // + buf*32768 + h*8192 (+4096 instr 1)
  u16* dB = &lds[16384 + tid * 8];

  // fragment addressing (per wave: 128x64 tile, 8x4 frags of 16x16x32)
  const int fr = lane & 15;              // m (A) / n (B) within 16
  // phys slot = k-slot(lane>>4) ^ ((row>>1)&3); row>>1&3 == (fr>>1)&3 for
  // all mi/ni/wm/wn (all multiples of 8 rows) -> lane-constant xor.
  const int xw = (((lane >> 4) ^ ((lane >> 1) & 3)) * 8);
  const int wm = (wv >> 2) * 128;        // wave m-offset (0 or 128)
  const int wn = (wv & 3) * 64;          // wave n-offset (0..192)
  const int rA = (wm + fr) * 32 + xw;    // u16 offset within A k-half
  const int rB = (wn + fr) * 32 + xw;

  f32x4 acc[8][4];
#pragma unroll
  for (int i = 0; i < 8; i++)
#pragma unroll
    for (int j = 0; j < 4; j++) acc[i][j] = (f32x4)0.f;

  const int NTt = K >> 6;                // BK=64 tiles

#define STAGE_A(BUF, KT, H) do {                                  \
    const u16* g_ = gA + (size_t)(KT) * 64 + (H) * 32;            \
    u16* d_ = dA + ((BUF) << 15) + (H) * 8192;                    \
    gload16(g_, d_); gload16(g_ + a128, d_ + 4096); } while (0)
#define STAGE_B(BUF, KT, H) do {                                  \
    const u16* g_ = gB + (size_t)(KT) * 64 + (H) * 32;            \
    u16* d_ = dB + ((BUF) << 15) + (H) * 8192;                    \
    gload16(g_, d_); gload16(g_ + b128, d_ + 4096); } while (0)
#define LOAD_AV(H, ROFF) _Pragma("unroll")                        \
    for (int i_ = 0; i_ < 4; i_++)                                \
      av[i_] = *(const bf16x8*)&lds[cb + (H) * 8192 + rA + (ROFF) + i_ * 512];
#define LOAD_BV(H) _Pragma("unroll")                              \
    for (int i_ = 0; i_ < 4; i_++)                                \
      bv[i_] = *(const bf16x8*)&lds[cb + 16384 + (H) * 8192 + rB + i_ * 512];
#define MFMA16(AR)                                                \
    __builtin_amdgcn_s_setprio(1);                                \
    _Pragma("unroll")                                             \
    for (int mi_ = 0; mi_ < 4; mi_++)                             \
      _Pragma("unroll")                                           \
      for (int ni_ = 0; ni_ < 4; ni_++)                           \
        acc[(AR) + mi_][ni_] = __builtin_amdgcn_mfma_f32_16x16x32_bf16( \
            av[mi_], bv[ni_], acc[(AR) + mi_][ni_], 0, 0, 0);     \
    __builtin_amdgcn_s_setprio(0);

  // prologue: tile 0, issue order Ak0,Bk0,Ak1,Bk1 (8 loads); retire k0.
  STAGE_A(0, 0, 0); STAGE_B(0, 0, 0); STAGE_A(0, 0, 1); STAGE_B(0, 0, 1);
  asm volatile("s_waitcnt vmcnt(4)" ::: "memory");
  __builtin_amdgcn_s_barrier();
  __builtin_amdgcn_sched_barrier(0);

  for (int kt = 0; kt < NTt; ++kt) {
    const int cb = (kt & 1) << 15;       // current buffer (u16 offset)
    const int nb = (kt & 1) ^ 1;         // staging buffer index
    const bool pf = (kt + 1 < NTt);
    bf16x8 av[4], bv[4];

    // ---- P1: k-half 0, mi 0-3 ---------------------------------------
    if (pf) STAGE_A(nb, kt + 1, 0);
    LOAD_AV(0, 0)
    LOAD_BV(0)
    MFMA16(0)

    // ---- P2: k-half 0, mi 4-7 (bv reused) ---------------------------
    if (pf) STAGE_B(nb, kt + 1, 0);
    LOAD_AV(0, 2048)
    MFMA16(4)

    // retire THIS tile's k1 halves (issued 2 phases ago last iteration);
    // k0(t+1) stays in flight (4 outstanding).
    if (pf) { asm volatile("s_waitcnt vmcnt(4)" ::: "memory"); }
    else    { asm volatile("s_waitcnt vmcnt(0)" ::: "memory"); }
    __builtin_amdgcn_s_barrier();
    __builtin_amdgcn_sched_barrier(0);

    // ---- P3: k-half 1, mi 0-3 ---------------------------------------
    if (pf) STAGE_A(nb, kt + 1, 1);
    LOAD_AV(1, 0)
    LOAD_BV(1)
    MFMA16(0)

    // ---- P4: k-half 1, mi 4-7 ---------------------------------------
    if (pf) STAGE_B(nb, kt + 1, 1);
    LOAD_AV(1, 2048)
    MFMA16(4)

    // boundary: retire k0(t+1) (issued 3-4 phases ago); k1(t+1) in flight.
    if (pf) {
      asm volatile("s_waitcnt vmcnt(4)" ::: "memory");
      __builtin_amdgcn_s_barrier();
      __builtin_amdgcn_sched_barrier(0);
    }
  }

  // epilogue: C/D layout col=lane&15, row=(lane>>4)*4+reg  [m89/m91 verified]
  const size_t cbase = (size_t)z * batchC;
  const int row0 = by * 256 + wm + (lane >> 4) * 4;
  const int col0 = bx * 256 + wn + fr;
#pragma unroll
  for (int mi = 0; mi < 8; mi++) {
#pragma unroll
    for (int i = 0; i < 4; i++) {
      const size_t roff = cbase + (size_t)(row0 + mi * 16 + i) * ldc + col0;
#pragma unroll
      for (int ni = 0; ni < 4; ni++) {
        float v = acc[mi][ni][i];
        if constexpr (BF16OUT)
          ((u16*)Cout)[roff + ni * 16] = f2bf(v);
        else
          ((float*)Cout)[roff + ni * 16] = v;
      }
    }
  }
#undef STAGE_A
#undef STAGE_B
#undef LOAD_AV
#undef LOAD_BV
#undef MFMA16
}

// One block per row of 2048 bf16 logits -> bf16 probabilities, IN PLACE.
__global__ __launch_bounds__(256) void softmax_rows_bf16(u16* __restrict__ SP) {
  const size_t row = blockIdx.x;
  us8* p = (us8*)(SP + row * 2048);
  const int t = threadIdx.x;
  us8 raw = p[t];
  float v[8];
#pragma unroll
  for (int i = 0; i < 8; i++) v[i] = bf2f(raw[i]);

  float m = v[0];
#pragma unroll
  for (int i = 1; i < 8; i++) m = fmaxf(m, v[i]);
#pragma unroll
  for (int o = 32; o; o >>= 1) m = fmaxf(m, __shfl_xor(m, o, 64));
  __shared__ float redm[4];
  if ((t & 63) == 0) redm[t >> 6] = m;
  __syncthreads();
  m = fmaxf(fmaxf(redm[0], redm[1]), fmaxf(redm[2], redm[3]));

  float sum = 0.f;
#pragma unroll
  for (int i = 0; i < 8; i++) { v[i] = __expf(v[i] - m); sum += v[i]; }
#pragma unroll
  for (int o = 32; o; o >>= 1) sum += __shfl_xor(sum, o, 64);
  __shared__ float reds[4];
  if ((t & 63) == 0) reds[t >> 6] = sum;
  __syncthreads();
  sum = reds[0] + reds[1] + reds[2] + reds[3];
  const float r = 1.0f / sum;

  us8 o;
#pragma unroll
  for (int i = 0; i < 8; i++) o[i] = f2bf(v[i] * r);
  p[t] = o;
}

extern "C" void kernel_launch(void* const* d_in, const int* in_sizes, int n_in,
                              void* d_out, int out_size, void* d_ws, size_t ws_size,
                              hipStream_t stream) {
  const float* x   = (const float*)d_in[0];  // [8,2048,1024]
  const float* ctx = (const float*)d_in[1];  // [8,2048,1024]
  const float* Wq  = (const float*)d_in[2];  // [1024,1024]
  const float* Wk  = (const float*)d_in[3];
  const float* Wv  = (const float*)d_in[4];
  float* out = (float*)d_out;                // [8,2048,1024] f32

  const size_t NT = 8ull * 2048 * 1024;      // 16,777,216 elements

  // d_ws layout (u16 elements; total 107 MB):
  //   xbf [0,NT)  cbf [NT,2NT)  -> both dead after projections -> S overlays
  //   Vt  [2NT,3NT)   Wqb/Wkb/Wvb [3NT, 3NT+3M)
  u16* wsu  = (u16*)d_ws;
  u16* xbf  = wsu;
  u16* cbf  = wsu + NT;
  u16* Sbuf = wsu;                 // overlays xbf+cbf (67 MB, 8 batches)
  u16* Vt   = wsu + 2 * NT;
  u16* Wqb  = wsu + 3 * NT;        // Wqb,Wkb,Wvb contiguous (1M elems each)
  // d_out doubles as bf16 Q [0,NT) and K [NT,2NT) until PV overwrites it.
  u16* Qbf = (u16*)d_out;

  dim3 blk(256), gblk(512);

  // 1) converts (2 dispatches)
  cvt_xc<<<dim3(32768), blk, 0, stream>>>((const float4*)x, (const float4*)ctx,
                                          (us4*)xbf, (us4*)cbf);
  cvt_w<<<dim3(3072), blk, 0, stream>>>((const float4*)Wq, (const float4*)Wk,
                                        (const float4*)Wv, (us4*)Wqb);

  // 2) [Q|K] projection: M=16384 N=1024 K=1024, z=0/1. nx*ny*nz=4*64*2=512.
  gemm_nt<true><<<dim3(512), gblk, 0, stream>>>(
      xbf, Wqb, Qbf, 1024, 1024, 1024, 1024,
      (long)NT, 1024L * 1024, (long)NT, 4, 64);
  // Vt[b,e,t] = Wv @ ctx_b^T : M=1024 N=2048 K=1024. nx*ny*nz=8*4*8=256.
  gemm_nt<true><<<dim3(256), gblk, 0, stream>>>(
      Wqb + 2 * 1024 * 1024, cbf, Vt, 1024, 1024, 2048, 1024,
      0L, 2048L * 1024, 1024L * 2048, 8, 4);

  // 3) S = Q@K^T : 8 batches, M=2048 N=2048 K=1024, bf16 out.
  //    nx*ny*nz = 8*8*8 = 512 blocks; slab=64 = one batch per XCD.
  gemm_nt<true><<<dim3(512), gblk, 0, stream>>>(
      Qbf, Qbf + NT, Sbuf, 1024, 1024, 2048, 1024,
      2048L * 1024, 2048L * 1024, 2048L * 2048, 8, 8);

  // 4) softmax in place: 16384 rows of 2048
  softmax_rows_bf16<<<dim3(16384), blk, 0, stream>>>(Sbuf);

  // 5) out = P@Vt^T : M=2048 N=1024 K=2048, f32 out. nx*ny*nz=4*8*8=256 ->
  //    one batch per XCD. Overwrites dead Q/K in d_out (stream-ordered).
  gemm_nt<false><<<dim3(256), gblk, 0, stream>>>(
      Sbuf, Vt, out, 2048, 2048, 1024, 2048,
      2048L * 2048, 1024L * 2048, 2048L * 1024, 4, 8);
}